// Round 16
// baseline (31.425 us; speedup 1.0000x reference)
//
#include <hip/hip_runtime.h>
#include <hip/hip_bf16.h>

typedef __attribute__((ext_vector_type(8))) short short8;
typedef __attribute__((ext_vector_type(4))) float f32x4;
typedef __attribute__((ext_vector_type(16))) float f32x16;

#define NROWS 65536             // BATCH * N_EDGES
#define EDGE_DIM 64
#define NODE_DIM 32
#define NN 1024                 // NODE_DIM^2

__device__ __forceinline__ short f2bf(float f) {
    unsigned u = __builtin_bit_cast(unsigned, f);
    u += 0x7FFFu + ((u >> 16) & 1u);            // round-to-nearest-even
    return (short)(u >> 16);
}

// R16 = R8's structure WITHOUT the VGPR cap (R8's 63us was the forced
// 64-VGPR spill — 200 MB scratch traffic — not the structure). 512 blocks x
// 512 threads x 128 edges. Wave wid owns i = wid*4..+3: 16 W frags in
// 64 VGPR, loaded once from f32 W (coalesced, L3-hot). Edges bf16-staged
// in 16 KB LDS (one barrier) -> no LDS block-cap; natural VGPR ~130 ->
// 3-4 waves/SIMD (vs R12's 2): the occupancy win every capped attempt
// (R10/R13/R15) failed to get. DS reads: 16/wave vs R12's 128.
// Fragment layout (verified R2..R15): frag = i*4+ks;
// frag[l][t] = bf16(W[ks*16 + (l>>5)*8 + t, i*32 + (l&31)]).
__global__ __launch_bounds__(512) void mp_fused(
    const float* __restrict__ node, const float* __restrict__ edge,
    const float* __restrict__ W, const float* __restrict__ bias,
    float* __restrict__ out) {
    // ldsE[eg(4)][ks(4)][lane(64)][8 shorts] = 1024 entries x 16 B = 16 KB
    __shared__ __align__(16) short ldsE[8192];

    const int tid = threadIdx.x;
    const int wid = tid >> 6;                 // 0..7 -> i-quad
    const int l   = tid & 63;
    const int e32 = l & 31;                   // lane's edge col (MFMA N)
    const int h   = l >> 5;                   // lane half (k-group / row offset)
    const int eb  = blockIdx.x * 128;         // block's first edge row

    // ---- W fragments for this wave's 4 i's -> 64 VGPR (one-time, L3-hot)
    short8 wfr[4][4];
#pragma unroll
    for (int il = 0; il < 4; ++il)
#pragma unroll
        for (int ks = 0; ks < 4; ++ks) {
            const float* wp = W + (size_t)(ks * 16 + h * 8) * NN
                                + (wid * 4 + il) * 32 + e32;
            short8 v;
#pragma unroll
            for (int t = 0; t < 8; ++t)
                v[t] = f2bf(wp[(size_t)t * NN]);   // coalesced across lanes
            wfr[il][ks] = v;
        }

    // ---- stage edge fragments: 1024 16B-entries, 2 per thread ----
#pragma unroll
    for (int k = 0; k < 2; ++k) {
        int n = k * 512 + tid;                // entry id
        int le = n & 63;                      // entry lane
        int ks = (n >> 6) & 3;
        int eg = n >> 8;
        const float* erow = edge + (size_t)(eb + eg * 32 + (le & 31)) * EDGE_DIM
                                 + ks * 16 + (le >> 5) * 8;
        f32x4 a = *reinterpret_cast<const f32x4*>(erow);
        f32x4 b = *reinterpret_cast<const f32x4*>(erow + 4);
        short8 v;
        v[0] = f2bf(a[0]); v[1] = f2bf(a[1]); v[2] = f2bf(a[2]); v[3] = f2bf(a[3]);
        v[4] = f2bf(b[0]); v[5] = f2bf(b[1]); v[6] = f2bf(b[2]); v[7] = f2bf(b[3]);
        *reinterpret_cast<short8*>(&ldsE[n * 8]) = v;
    }
    __syncthreads();                          // the ONLY barrier

#pragma unroll
    for (int eg = 0; eg < 4; ++eg) {
        // edge B-fragments for this 32-edge group (conflict-free ds_read_b128)
        short8 ef0 = *reinterpret_cast<const short8*>(&ldsE[((eg * 4 + 0) * 64 + l) * 8]);
        short8 ef1 = *reinterpret_cast<const short8*>(&ldsE[((eg * 4 + 1) * 64 + l) * 8]);
        short8 ef2 = *reinterpret_cast<const short8*>(&ldsE[((eg * 4 + 2) * 64 + l) * 8]);
        short8 ef3 = *reinterpret_cast<const short8*>(&ldsE[((eg * 4 + 3) * 64 + l) * 8]);

        // node values: acc reg r=q*4+rr -> j = q*8 + h*4 + rr (L1/L2-hot)
        const float* nrow = node + (size_t)(eb + eg * 32 + e32) * NODE_DIM;
        f32x4 n0 = *reinterpret_cast<const f32x4*>(nrow + 0 * 8 + h * 4);
        f32x4 n1 = *reinterpret_cast<const f32x4*>(nrow + 1 * 8 + h * 4);
        f32x4 n2 = *reinterpret_cast<const f32x4*>(nrow + 2 * 8 + h * 4);
        f32x4 n3 = *reinterpret_cast<const f32x4*>(nrow + 3 * 8 + h * 4);

        f32x4 vq;
#pragma unroll
        for (int il = 0; il < 4; ++il) {
            const int i = wid * 4 + il;
            // bias as C-init: reg q*4+rr -> row q*8 + h*4 + rr (L1-hot)
            f32x16 acc;
#pragma unroll
            for (int q = 0; q < 4; ++q) {
                f32x4 bq = *reinterpret_cast<const f32x4*>(bias + i * 32 + q * 8 + h * 4);
                acc[q * 4 + 0] = bq[0]; acc[q * 4 + 1] = bq[1];
                acc[q * 4 + 2] = bq[2]; acc[q * 4 + 3] = bq[3];
            }
            acc = __builtin_amdgcn_mfma_f32_32x32x16_bf16(wfr[il][0], ef0, acc, 0, 0, 0);
            acc = __builtin_amdgcn_mfma_f32_32x32x16_bf16(wfr[il][1], ef1, acc, 0, 0, 0);
            acc = __builtin_amdgcn_mfma_f32_32x32x16_bf16(wfr[il][2], ef2, acc, 0, 0, 0);
            acc = __builtin_amdgcn_mfma_f32_32x32x16_bf16(wfr[il][3], ef3, acc, 0, 0, 0);

            // relu + matvec, 4 independent partials (chain depth 4)
            float s0 = 0.f, s1 = 0.f, s2 = 0.f, s3 = 0.f;
#pragma unroll
            for (int rr = 0; rr < 4; ++rr) {
                s0 += fmaxf(acc[rr],      0.f) * n0[rr];
                s1 += fmaxf(acc[4 + rr],  0.f) * n1[rr];
                s2 += fmaxf(acc[8 + rr],  0.f) * n2[rr];
                s3 += fmaxf(acc[12 + rr], 0.f) * n3[rr];
            }
            float p = (s0 + s1) + (s2 + s3);
            p += __shfl_xor(p, 32);           // add partner half's 16 j's
            vq[il] = p;
        }
        // store msg[eb+eg*32+l, wid*4 .. +3] (16B per lane<32)
        if (l < 32)
            *reinterpret_cast<f32x4*>(out + (size_t)(eb + eg * 32 + l) * NODE_DIM
                                      + wid * 4) = vq;
    }
}

extern "C" void kernel_launch(void* const* d_in, const int* in_sizes, int n_in,
                              void* d_out, int out_size, void* d_ws, size_t ws_size,
                              hipStream_t stream) {
    const float* node = (const float*)d_in[0];  // [16,4096,32] f32
    const float* edge = (const float*)d_in[1];  // [16,4096,64] f32
    const float* W    = (const float*)d_in[2];  // [64,1024] f32
    const float* bias = (const float*)d_in[3];  // [1024] f32
    float* out = (float*)d_out;                 // [16,4096,32] f32

    mp_fused<<<dim3(NROWS / 128), dim3(512), 0, stream>>>(node, edge, W, bias, out);
}

// Round 17
// 27.296 us; speedup vs baseline: 1.1513x; 1.1513x over previous
//
#include <hip/hip_runtime.h>
#include <hip/hip_bf16.h>

typedef __attribute__((ext_vector_type(8))) short short8;
typedef __attribute__((ext_vector_type(4))) float f32x4;
typedef __attribute__((ext_vector_type(16))) float f32x16;

#define NROWS 65536             // BATCH * N_EDGES
#define EDGE_DIM 64
#define NODE_DIM 32
#define NN 1024                 // NODE_DIM^2

__device__ __forceinline__ short f2bf(float f) {
    unsigned u = __builtin_bit_cast(unsigned, f);
    u += 0x7FFFu + ((u >> 16) & 1u);            // round-to-nearest-even
    return (short)(u >> 16);
}

// R17 = R15 WITHOUT the launch_bounds min-occupancy arg (the last untested
// cell: i-split + no VGPR cap). Grid 512 = (echunk 0..255) x (ihalf 0..1):
// block = 256 edges x 16 i's, 64 KB LDS -> 2 blocks/CU IF natural VGPR<=128
// (single-group body, est. ~110). Every capped variant regressed (R8/R13/
// R15); this tests whether the cap, not the split, was R15's poison.
// Body byte-identical to R12 (best, 23.8 us). Fragment layout (verified
// R2..R16): frag = i*4+ks; lds[(frag_local*64+l)*8+t] =
// bf16(W[ks*16 + (l>>5)*8 + t, i*32 + (l&31)]).
__global__ __launch_bounds__(512) void mp_fused(
    const float* __restrict__ node, const float* __restrict__ edge,
    const float* __restrict__ W, const float* __restrict__ bias,
    float* __restrict__ out) {
    __shared__ __align__(16) short ldsW[32768];   // 64 KB: this i-half's W

    const int tid   = threadIdx.x;
    const int wid   = tid >> 6;               // 0..7 -> 32-edge group
    const int l     = tid & 63;
    const int e32   = l & 31;                 // lane's edge col (MFMA N)
    const int h     = l >> 5;                 // lane half (k-group / row offset)

    const int bid    = blockIdx.x;
    const int echunk = bid & 255;             // 256-edge chunk
    const int ihalf  = bid >> 8;              // 0..1
    const int ibase  = ihalf * 16;
    const int eb     = echunk * 256 + wid * 32;
    const int e      = eb + e32;

    // ---- in-block W pack: wave wid packs local frags [wid*8, wid*8+8) ----
#pragma unroll
    for (int m = 0; m < 8; ++m) {
        const int fl = wid * 8 + m;           // local frag = il*4 + ks
        const int i  = ibase + (fl >> 2);
        const int ks = fl & 3;
        const float* wp = W + (size_t)(ks * 16 + h * 8) * NN + i * 32 + e32;
        short8 v;
#pragma unroll
        for (int t = 0; t < 8; ++t)
            v[t] = f2bf(wp[(size_t)t * NN]);  // coalesced across lanes per t
        *reinterpret_cast<short8*>(&ldsW[((size_t)fl * 64 + l) * 8]) = v;
    }

    // ---- per-lane inputs (overlap the pack's VMEM stream) ----
    // ef[ks]: k = h*8+t -> edge[e, ks*16 + h*8 + t]
    // nv[q*4+rr]: acc reg r=q*4+rr -> j = q*8 + h*4 + rr
    short8 ef[4];
    float  nv[16];
    const float* erow = edge + (size_t)e * EDGE_DIM;
#pragma unroll
    for (int ks = 0; ks < 4; ++ks) {
        f32x4 a = *reinterpret_cast<const f32x4*>(erow + ks * 16 + h * 8);
        f32x4 b = *reinterpret_cast<const f32x4*>(erow + ks * 16 + h * 8 + 4);
        short8 v;
        v[0] = f2bf(a[0]); v[1] = f2bf(a[1]); v[2] = f2bf(a[2]); v[3] = f2bf(a[3]);
        v[4] = f2bf(b[0]); v[5] = f2bf(b[1]); v[6] = f2bf(b[2]); v[7] = f2bf(b[3]);
        ef[ks] = v;
    }
    const float* nrow = node + (size_t)e * NODE_DIM;
#pragma unroll
    for (int q = 0; q < 4; ++q) {
        f32x4 n = *reinterpret_cast<const f32x4*>(nrow + q * 8 + h * 4);
        nv[q * 4 + 0] = n[0]; nv[q * 4 + 1] = n[1];
        nv[q * 4 + 2] = n[2]; nv[q * 4 + 3] = n[3];
    }

    __syncthreads();                          // the ONLY barrier

    float* orow = out + (size_t)(eb + (l & 31)) * NODE_DIM + ibase;

#pragma unroll 2
    for (int iq = 0; iq < 4; ++iq) {
        f32x4 vq;
#pragma unroll
        for (int r = 0; r < 4; ++r) {
            const int il = iq * 4 + r;        // local i
            const int i  = ibase + il;
            const short* wp = &ldsW[(size_t)il * 2048 + l * 8];
            short8 w0 = *reinterpret_cast<const short8*>(wp + 0 * 512);
            short8 w1 = *reinterpret_cast<const short8*>(wp + 1 * 512);
            short8 w2 = *reinterpret_cast<const short8*>(wp + 2 * 512);
            short8 w3 = *reinterpret_cast<const short8*>(wp + 3 * 512);

            // bias as C-init: reg q*4+rr -> row q*8 + h*4 + rr (L1-hot)
            f32x16 acc;
#pragma unroll
            for (int q = 0; q < 4; ++q) {
                f32x4 bq = *reinterpret_cast<const f32x4*>(bias + i * 32 + q * 8 + h * 4);
                acc[q * 4 + 0] = bq[0]; acc[q * 4 + 1] = bq[1];
                acc[q * 4 + 2] = bq[2]; acc[q * 4 + 3] = bq[3];
            }

            acc = __builtin_amdgcn_mfma_f32_32x32x16_bf16(w0, ef[0], acc, 0, 0, 0);
            acc = __builtin_amdgcn_mfma_f32_32x32x16_bf16(w1, ef[1], acc, 0, 0, 0);
            acc = __builtin_amdgcn_mfma_f32_32x32x16_bf16(w2, ef[2], acc, 0, 0, 0);
            acc = __builtin_amdgcn_mfma_f32_32x32x16_bf16(w3, ef[3], acc, 0, 0, 0);

            // relu + matvec, 4 independent partials (chain depth 4)
            float s0 = 0.f, s1 = 0.f, s2 = 0.f, s3 = 0.f;
#pragma unroll
            for (int rr = 0; rr < 4; ++rr) {
                s0 += fmaxf(acc[rr],      0.f) * nv[rr];
                s1 += fmaxf(acc[4 + rr],  0.f) * nv[4 + rr];
                s2 += fmaxf(acc[8 + rr],  0.f) * nv[8 + rr];
                s3 += fmaxf(acc[12 + rr], 0.f) * nv[12 + rr];
            }
            float p = (s0 + s1) + (s2 + s3);
            p += __shfl_xor(p, 32);           // add partner half's 16 j's
            vq[r] = p;
        }
        if (l < 32)
            *reinterpret_cast<f32x4*>(orow + iq * 4) = vq;  // msg[e, ibase+iq*4..]
    }
}

extern "C" void kernel_launch(void* const* d_in, const int* in_sizes, int n_in,
                              void* d_out, int out_size, void* d_ws, size_t ws_size,
                              hipStream_t stream) {
    const float* node = (const float*)d_in[0];  // [16,4096,32] f32
    const float* edge = (const float*)d_in[1];  // [16,4096,64] f32
    const float* W    = (const float*)d_in[2];  // [64,1024] f32
    const float* bias = (const float*)d_in[3];  // [1024] f32
    float* out = (float*)d_out;                 // [16,4096,32] f32

    mp_fused<<<dim3(512), dim3(512), 0, stream>>>(node, edge, W, bias, out);
}

// Round 18
// 23.977 us; speedup vs baseline: 1.3106x; 1.1384x over previous
//
#include <hip/hip_runtime.h>
#include <hip/hip_bf16.h>

typedef __attribute__((ext_vector_type(8))) short short8;
typedef __attribute__((ext_vector_type(4))) float f32x4;
typedef __attribute__((ext_vector_type(16))) float f32x16;

#define NROWS 65536             // BATCH * N_EDGES
#define EDGE_DIM 64
#define NODE_DIM 32
#define NN 1024                 // NODE_DIM^2

__device__ __forceinline__ short f2bf(float f) {
    unsigned u = __builtin_bit_cast(unsigned, f);
    u += 0x7FFFu + ((u >> 16) & 1u);            // round-to-nearest-even
    return (short)(u >> 16);
}

// R18 = R12 (best, 23.8 us) + explicit 1-deep software pipeline (T14,
// issue-early): i+1's 4 ds_read_b128 (W frags) + 4 bias loads are issued
// BEFORE i's MFMA chain + epilogue, so the ~140-cyc epilogue covers their
// latency (R12's diagnosed wall: ~16 us of exposed dependent-load latency
// at 2 waves/SIMD). Both loops fully unrolled -> all wbuf/bbuf indices
// compile-time (no scratch). VGPR ~160 at 2 waves/SIMD (256 budget): safe.
// Everything else identical to R12: 256 blocks x 512 threads, in-block W
// pack to 128 KB LDS, ONE barrier, 32-edge waves, single-acc body.
// Fragment layout (verified R2..R17): frag = i*4+ks;
// ldsW[(frag*64+l)*8+t] = bf16(W[ks*16 + (l>>5)*8 + t, i*32 + (l&31)]).
__global__ __launch_bounds__(512) void mp_fused(
    const float* __restrict__ node, const float* __restrict__ edge,
    const float* __restrict__ W, const float* __restrict__ bias,
    float* __restrict__ out) {
    __shared__ __align__(16) short ldsW[65536];   // 128 KB: full packed W

    const int tid = threadIdx.x;
    const int wid = tid >> 6;                 // 0..7
    const int l   = tid & 63;
    const int e32 = l & 31;                   // lane's edge col (MFMA N)
    const int h   = l >> 5;                   // lane half (k-group / row offset)
    const int eb  = blockIdx.x * 256 + wid * 32;
    const int e   = eb + e32;

    // ---- in-block W pack: wave wid packs frags [wid*16, wid*16+16) ----
#pragma unroll
    for (int m = 0; m < 16; ++m) {
        const int frag = wid * 16 + m;        // frag = i*4 + ks
        const int i  = frag >> 2;
        const int ks = frag & 3;
        const float* wp = W + (size_t)(ks * 16 + h * 8) * NN + i * 32 + e32;
        short8 v;
#pragma unroll
        for (int t = 0; t < 8; ++t)
            v[t] = f2bf(wp[(size_t)t * NN]);  // coalesced across lanes per t
        *reinterpret_cast<short8*>(&ldsW[((size_t)frag * 64 + l) * 8]) = v;
    }

    // ---- per-lane inputs (overlap the pack's VMEM stream) ----
    // ef[ks]: k = h*8+t -> edge[e, ks*16 + h*8 + t]
    // nv[q*4+rr]: acc reg r=q*4+rr -> j = q*8 + h*4 + rr
    short8 ef[4];
    float  nv[16];
    const float* erow = edge + (size_t)e * EDGE_DIM;
#pragma unroll
    for (int ks = 0; ks < 4; ++ks) {
        f32x4 a = *reinterpret_cast<const f32x4*>(erow + ks * 16 + h * 8);
        f32x4 b = *reinterpret_cast<const f32x4*>(erow + ks * 16 + h * 8 + 4);
        short8 v;
        v[0] = f2bf(a[0]); v[1] = f2bf(a[1]); v[2] = f2bf(a[2]); v[3] = f2bf(a[3]);
        v[4] = f2bf(b[0]); v[5] = f2bf(b[1]); v[6] = f2bf(b[2]); v[7] = f2bf(b[3]);
        ef[ks] = v;
    }
    const float* nrow = node + (size_t)e * NODE_DIM;
#pragma unroll
    for (int q = 0; q < 4; ++q) {
        f32x4 n = *reinterpret_cast<const f32x4*>(nrow + q * 8 + h * 4);
        nv[q * 4 + 0] = n[0]; nv[q * 4 + 1] = n[1];
        nv[q * 4 + 2] = n[2]; nv[q * 4 + 3] = n[3];
    }

    __syncthreads();                          // the ONLY barrier

    float* orow = out + (size_t)(eb + (l & 31)) * NODE_DIM;

    // ---- software-pipelined i-loop (depth 1): prime i=0 ----
    short8 wbuf[2][4];                        // [parity][ks], 32 VGPR
    f32x4  bbuf[2][4];                        // [parity][q],  32 VGPR
    {
        const short* wp0 = &ldsW[(size_t)0 * 2048 + l * 8];
#pragma unroll
        for (int q = 0; q < 4; ++q) {
            wbuf[0][q] = *reinterpret_cast<const short8*>(wp0 + q * 512);
            bbuf[0][q] = *reinterpret_cast<const f32x4*>(bias + 0 * 32 + q * 8 + h * 4);
        }
    }

#pragma unroll
    for (int iq = 0; iq < 8; ++iq) {
        f32x4 vq;
#pragma unroll
        for (int r = 0; r < 4; ++r) {
            const int i   = iq * 4 + r;
            const int cur = i & 1;
            const int nxt = cur ^ 1;
            // issue-early: prefetch i+1's W frags + bias before i's compute
            if (i < 31) {
                const short* wp = &ldsW[(size_t)(i + 1) * 2048 + l * 8];
#pragma unroll
                for (int q = 0; q < 4; ++q) {
                    wbuf[nxt][q] = *reinterpret_cast<const short8*>(wp + q * 512);
                    bbuf[nxt][q] = *reinterpret_cast<const f32x4*>(
                        bias + (i + 1) * 32 + q * 8 + h * 4);
                }
            }
            // bias as C-init: reg q*4+rr -> row q*8 + h*4 + rr
            f32x16 acc;
#pragma unroll
            for (int q = 0; q < 4; ++q) {
                acc[q * 4 + 0] = bbuf[cur][q][0]; acc[q * 4 + 1] = bbuf[cur][q][1];
                acc[q * 4 + 2] = bbuf[cur][q][2]; acc[q * 4 + 3] = bbuf[cur][q][3];
            }

            acc = __builtin_amdgcn_mfma_f32_32x32x16_bf16(wbuf[cur][0], ef[0], acc, 0, 0, 0);
            acc = __builtin_amdgcn_mfma_f32_32x32x16_bf16(wbuf[cur][1], ef[1], acc, 0, 0, 0);
            acc = __builtin_amdgcn_mfma_f32_32x32x16_bf16(wbuf[cur][2], ef[2], acc, 0, 0, 0);
            acc = __builtin_amdgcn_mfma_f32_32x32x16_bf16(wbuf[cur][3], ef[3], acc, 0, 0, 0);

            // relu + matvec, 4 independent partials (chain depth 4)
            float s0 = 0.f, s1 = 0.f, s2 = 0.f, s3 = 0.f;
#pragma unroll
            for (int rr = 0; rr < 4; ++rr) {
                s0 += fmaxf(acc[rr],      0.f) * nv[rr];
                s1 += fmaxf(acc[4 + rr],  0.f) * nv[4 + rr];
                s2 += fmaxf(acc[8 + rr],  0.f) * nv[8 + rr];
                s3 += fmaxf(acc[12 + rr], 0.f) * nv[12 + rr];
            }
            float p = (s0 + s1) + (s2 + s3);
            p += __shfl_xor(p, 32);           // add partner half's 16 j's
            vq[r] = p;
        }
        if (l < 32)
            *reinterpret_cast<f32x4*>(orow + iq * 4) = vq;  // msg[e, iq*4..+3]
    }
}

extern "C" void kernel_launch(void* const* d_in, const int* in_sizes, int n_in,
                              void* d_out, int out_size, void* d_ws, size_t ws_size,
                              hipStream_t stream) {
    const float* node = (const float*)d_in[0];  // [16,4096,32] f32
    const float* edge = (const float*)d_in[1];  // [16,4096,64] f32
    const float* W    = (const float*)d_in[2];  // [64,1024] f32
    const float* bias = (const float*)d_in[3];  // [1024] f32
    float* out = (float*)d_out;                 // [16,4096,32] f32

    mp_fused<<<dim3(NROWS / 256), dim3(512), 0, stream>>>(node, edge, W, bias, out);
}